// Round 5
// baseline (717.308 us; speedup 1.0000x reference)
//
#include <hip/hip_runtime.h>
#include <cstdint>
#include <cstddef>

typedef __bf16 bf16;
typedef __bf16 bf16x8 __attribute__((ext_vector_type(8)));
typedef float  f32x4  __attribute__((ext_vector_type(4)));

#define MFMA16(a, b, c) __builtin_amdgcn_mfma_f32_16x16x32_bf16((a), (b), (c), 0, 0, 0)

// async global->LDS, 16B per lane. LDS dest is wave-uniform base + lane*16.
__device__ __forceinline__ void async16(const bf16* g, bf16* l) {
  __builtin_amdgcn_global_load_lds(
      (const __attribute__((address_space(1))) unsigned int*)g,
      (__attribute__((address_space(3))) unsigned int*)l, 16, 0, 0);
}

// ---------------- elementwise cast fp32 -> bf16 (4 elems/thread) ----------------
__global__ __launch_bounds__(256) void k_cast(const float* __restrict__ x, bf16* __restrict__ y) {
  size_t i = ((size_t)blockIdx.x * 256 + threadIdx.x) * 4;
  float4 a = *(const float4*)(x + i);
  union { bf16 h[4]; uint2 u; } pk;
  pk.h[0] = (bf16)a.x; pk.h[1] = (bf16)a.y; pk.h[2] = (bf16)a.z; pk.h[3] = (bf16)a.w;
  *(uint2*)(y + i) = pk.u;
}

// ---------------- batched W[K,N] fp32 -> WT[N,K] bf16 for the 4 input projections ----------------
__global__ __launch_bounds__(256) void k_wt_all(const float* __restrict__ Wq,
                                                const float* __restrict__ Wk,
                                                const float* __restrict__ Wv,
                                                const float* __restrict__ Wg,
                                                bf16* __restrict__ WT) {
  const int K = 2048;
  __shared__ float tile[32][33];
  int z = blockIdx.z;
  const float* W; bf16* dst; int N;
  if (z == 0)      { W = Wq; dst = WT;                          N = 2048; }
  else if (z == 1) { W = Wk; dst = WT + (size_t)2048 * 2048;    N = 2048; }
  else if (z == 2) { W = Wv; dst = WT + (size_t)4096 * 2048;    N = 4096; }
  else             { W = Wg; dst = WT + (size_t)8192 * 2048;    N = 4096; }
  int n0 = blockIdx.x << 5;
  if (n0 >= N) return;
  int k0 = blockIdx.y << 5;
  int r = threadIdx.x >> 5, c = threadIdx.x & 31;
#pragma unroll
  for (int p = 0; p < 4; p++)
    tile[r + p * 8][c] = W[(size_t)(k0 + r + p * 8) * N + n0 + c];
  __syncthreads();
#pragma unroll
  for (int p = 0; p < 4; p++) {
    int nn = r + p * 8;
    dst[(size_t)(n0 + nn) * K + k0 + c] = (bf16)tile[c][nn];
  }
}

// ---------------- W[K,N] fp32 -> WT[N,K] bf16, tiled transpose (single) ----------------
__global__ __launch_bounds__(256) void k_transpose_cast(const float* __restrict__ W,
                                                        bf16* __restrict__ WT, int K, int N) {
  __shared__ float tile[32][33];
  int k0 = blockIdx.y << 5, n0 = blockIdx.x << 5;
  int r = threadIdx.x >> 5, c = threadIdx.x & 31;
#pragma unroll
  for (int p = 0; p < 4; p++)
    tile[r + p * 8][c] = W[(size_t)(k0 + r + p * 8) * N + n0 + c];
  __syncthreads();
#pragma unroll
  for (int p = 0; p < 4; p++) {
    int nn = r + p * 8;
    WT[(size_t)(n0 + nn) * K + k0 + c] = (bf16)tile[c][nn];
  }
}

// ---- per-(b,h) bf16 transpose: src[(b,t),h,d] (d<D) -> dst[(b,h),d,t] ----
__global__ __launch_bounds__(256) void k_transpose_bh(const bf16* __restrict__ src,
                                                      bf16* __restrict__ dst, int D) {
  __shared__ bf16 tile[32][33];
  int bh = blockIdx.z;
  int b = bh >> 3, h = bh & 7;
  int d0 = blockIdx.x << 5, t0 = blockIdx.y << 5;
  int r = threadIdx.x >> 5, c = threadIdx.x & 31;
#pragma unroll
  for (int p = 0; p < 4; p++)
    tile[r + p * 8][c] = src[((size_t)((b * 2048 + t0 + r + p * 8) * 8 + h)) * D + d0 + c];
  __syncthreads();
#pragma unroll
  for (int p = 0; p < 4; p++)
    dst[((size_t)(bh * D + d0 + r + p * 8)) * 2048 + t0 + c] = tile[c][r + p * 8];
}

// ---------------- fused projection GEMM: [4096,2048] x WT[12288,2048]^T ----------------
__global__ __launch_bounds__(256) void k_gemm_qkvg(const bf16* __restrict__ A,
                                                   const bf16* __restrict__ Bt,
                                                   bf16* __restrict__ qb, bf16* __restrict__ kb,
                                                   bf16* __restrict__ vbuf, bf16* __restrict__ gb) {
  const int K = 2048;
  __shared__ bf16 a_lds[128 * 64];
  __shared__ bf16 b_lds[128 * 64];
  int tid = threadIdx.x;
  int wave = tid >> 6, lane = tid & 63, quad = lane >> 4, l16 = lane & 15;
  int wr = wave >> 1, wc = wave & 1;
  int m0 = blockIdx.y << 7, n0 = blockIdx.x << 7;
  f32x4 acc[4][4] = {};
  int rl = tid >> 3;                       // local row 0..31 (row&7 == rl&7 for all i)
  int sb = (tid & 7) ^ (rl & 7);           // swizzled source block
  const bf16* ag = A + (size_t)(m0 + rl) * K + sb * 8;
  const bf16* bg = Bt + (size_t)(n0 + rl) * K + sb * 8;
  bf16* al = a_lds + wave * 512;
  bf16* bl = b_lds + wave * 512;
  int sw = (l16 & 7) << 3;                 // read-side XOR (bf16 elems)
  for (int kt = 0; kt < K; kt += 64) {
#pragma unroll
    for (int i = 0; i < 4; i++) {
      async16(ag + (size_t)i * 32 * K, al + i * 2048);
      async16(bg + (size_t)i * 32 * K, bl + i * 2048);
    }
    ag += 64; bg += 64;
    __syncthreads();
#pragma unroll
    for (int kk = 0; kk < 2; kk++) {
      int bo = ((kk * 4 + quad) << 3) ^ sw;
      bf16x8 af[4], bfv[4];
#pragma unroll
      for (int mt = 0; mt < 4; mt++)
        af[mt] = *(const bf16x8*)&a_lds[(wr * 64 + mt * 16 + l16) * 64 + bo];
#pragma unroll
      for (int nt = 0; nt < 4; nt++)
        bfv[nt] = *(const bf16x8*)&b_lds[(wc * 64 + nt * 16 + l16) * 64 + bo];
#pragma unroll
      for (int mt = 0; mt < 4; mt++)
#pragma unroll
        for (int nt = 0; nt < 4; nt++)
          acc[mt][nt] = MFMA16(af[mt], bfv[nt], acc[mt][nt]);
    }
    __syncthreads();
  }
  // segmented epilogue (wave-uniform segment select)
  bf16* dst; int ldd, c0;
  if (n0 < 2048)       { dst = qb;   ldd = 2048; c0 = n0; }
  else if (n0 < 4096)  { dst = kb;   ldd = 2048; c0 = n0 - 2048; }
  else if (n0 < 8192)  { dst = vbuf; ldd = 4096; c0 = n0 - 4096; }
  else                 { dst = gb;   ldd = 4096; c0 = n0 - 8192; }
#pragma unroll
  for (int mt = 0; mt < 4; mt++)
#pragma unroll
    for (int nt = 0; nt < 4; nt++)
#pragma unroll
      for (int r = 0; r < 4; r++) {
        int row = m0 + wr * 64 + mt * 16 + quad * 4 + r;
        int col = c0 + wc * 64 + nt * 16 + l16;
        dst[(size_t)row * ldd + col] = (bf16)acc[mt][nt][r];
      }
}

// ---------------- GEMM: C[M,N] = A[M,K] * Bt[N,K]^T  (bf16 in, fp32 out) ----------------
__global__ __launch_bounds__(256) void k_gemm_bt(const bf16* __restrict__ A,
                                                 const bf16* __restrict__ Bt,
                                                 float* __restrict__ C, int M, int N, int K) {
  __shared__ bf16 a_lds[128 * 64];
  __shared__ bf16 b_lds[128 * 64];
  int tid = threadIdx.x;
  int wave = tid >> 6, lane = tid & 63, quad = lane >> 4, l16 = lane & 15;
  int wr = wave >> 1, wc = wave & 1;
  int m0 = blockIdx.y << 7, n0 = blockIdx.x << 7;
  f32x4 acc[4][4] = {};
  int rl = tid >> 3;
  int sb = (tid & 7) ^ (rl & 7);
  const bf16* ag = A + (size_t)(m0 + rl) * K + sb * 8;
  const bf16* bg = Bt + (size_t)(n0 + rl) * K + sb * 8;
  bf16* al = a_lds + wave * 512;
  bf16* bl = b_lds + wave * 512;
  int sw = (l16 & 7) << 3;
  for (int kt = 0; kt < K; kt += 64) {
#pragma unroll
    for (int i = 0; i < 4; i++) {
      async16(ag + (size_t)i * 32 * K, al + i * 2048);
      async16(bg + (size_t)i * 32 * K, bl + i * 2048);
    }
    ag += 64; bg += 64;
    __syncthreads();
#pragma unroll
    for (int kk = 0; kk < 2; kk++) {
      int bo = ((kk * 4 + quad) << 3) ^ sw;
      bf16x8 af[4], bfv[4];
#pragma unroll
      for (int mt = 0; mt < 4; mt++)
        af[mt] = *(const bf16x8*)&a_lds[(wr * 64 + mt * 16 + l16) * 64 + bo];
#pragma unroll
      for (int nt = 0; nt < 4; nt++)
        bfv[nt] = *(const bf16x8*)&b_lds[(wc * 64 + nt * 16 + l16) * 64 + bo];
#pragma unroll
      for (int mt = 0; mt < 4; mt++)
#pragma unroll
        for (int nt = 0; nt < 4; nt++)
          acc[mt][nt] = MFMA16(af[mt], bfv[nt], acc[mt][nt]);
    }
    __syncthreads();
  }
#pragma unroll
  for (int mt = 0; mt < 4; mt++)
#pragma unroll
    for (int nt = 0; nt < 4; nt++)
#pragma unroll
      for (int r = 0; r < 4; r++) {
        int row = m0 + wr * 64 + mt * 16 + quad * 4 + r;
        int col = n0 + wc * 64 + nt * 16 + l16;
        C[(size_t)row * N + col] = acc[mt][nt][r];
      }
}

// ------- merged rotary (in-place, bf16): blocks [0,16384) -> q (*DK^-0.5),
// [16384,32768) -> k (fold gamma^(63-(t&63))) -------
__global__ __launch_bounds__(256) void k_rotary2(bf16* __restrict__ q, bf16* __restrict__ k) {
  int bid = blockIdx.x;
  bf16* x; int kmode;
  if (bid < 16384) { x = q; kmode = 0; }
  else             { x = k; kmode = 1; bid -= 16384; }
  int tid = threadIdx.x;
  int row = bid * 2 + (tid >> 7);
  int j = tid & 127;
  int t = (row >> 3) & 2047;
  int h = row & 7;
  float scale;
  if (kmode) {
    float lg = log2f(1.f - exp2f(-5.f - (float)h));
    scale = exp2f(lg * (float)(63 - (t & 63)));
  } else {
    scale = 0.0625f;
  }
  float inv = exp2f(-0.10381025296522976f * (float)j);
  float ang = (float)t * inv;
  float s, c;
  sincosf(ang, &s, &c);
  size_t base = (size_t)row * 256;
  float x1 = (float)x[base + j], x2 = (float)x[base + j + 128];
  x[base + j]       = (bf16)((x1 * c - x2 * s) * scale);
  x[base + j + 128] = (bf16)((x2 * c + x1 * s) * scale);
}

// ---------------- retention scan, slim-LDS / 2 WG-per-CU version ----------------
// grid 512: gid = vb*32 + (b*16 + h*2 + kh); vb in [0,16) owns 32 v-cols; kh in {0,1}
// owns 128 kd rows (partials sum in normgate). q,k fragments read DIRECTLY from
// global (L1/L2-shared across the 16 sibling vb-WGs and 4 waves). kT,vT staged via
// async16 double-buffered with XOR block swizzle. St (bf16 state snapshot) is the
// only other LDS, single-buffered with a second barrier.
// LDS = 32K(ktA) + 8K(vtA) + 8.7K(StA) = 48.9 KB -> 3 WG/CU capacity, 2 resident.
__global__ __launch_bounds__(256) void k_retention(const bf16* __restrict__ q,
                                                   const bf16* __restrict__ k,
                                                   const bf16* __restrict__ kT,
                                                   const bf16* __restrict__ vT,
                                                   bf16* __restrict__ o0,
                                                   bf16* __restrict__ o1) {
  __shared__ bf16 ktA[2][128 * 64];  // [kd][c]
  __shared__ bf16 vtA[2][32 * 64];   // [vd][c]
  __shared__ bf16 StA[32 * 136];     // [vd][kd] +8 pad, single-buffered

  int gid = blockIdx.x;
  int kh = gid & 1, h = (gid >> 1) & 7, b = (gid >> 4) & 1, vb = gid >> 5;
  int bh = b * 8 + h;
  bf16* oout = kh ? o1 : o0;
  int tid = threadIdx.x, lane = tid & 63, wave = tid >> 6, quad = lane >> 4, l16 = lane & 15;
  float gamma = 1.f - exp2f(-5.f - (float)h);
  float lg = log2f(gamma);
  float gC = exp2f(64.f * lg);
  int iRow = wave * 16 + l16;                       // i for A^T(n) and A@v(m)
  float ei = exp2f(lg * (float)(iRow - 63));
  float qd[4];
#pragma unroll
  for (int r = 0; r < 4; r++) qd[r] = exp2f(lg * (float)(wave * 16 + quad * 4 + r + 1));
  int sw = (l16 & 7) << 3;                          // read-side XOR (bf16 elems)

  // direct-global q/k row bases (row stride 2048 elems = 8 heads * 256)
  const bf16* qrow = q + ((size_t)(b * 2048) * 8 + h) * 256 + kh * 128;
  const bf16* krow = k + ((size_t)(b * 2048) * 8 + h) * 256 + kh * 128;

  f32x4 S[2][2];  // a(kd-tile: wave*32+a*16) x bb(vd-tile: bb*16)
#pragma unroll
  for (int a = 0; a < 2; a++)
#pragma unroll
    for (int bb = 0; bb < 2; bb++) S[a][bb] = (f32x4){0.f, 0.f, 0.f, 0.f};

  // async staging of kT/vT slices for one chunk (20 x 1KB instrs over 4 waves)
  auto stage = [&](int t0, int p) {
#pragma unroll 1
    for (int s = wave; s < 20; s += 4) {
      if (s < 16) {
        int kd = s * 8 + (lane >> 3);
        int blk = (lane & 7) ^ (kd & 7);
        async16(kT + ((size_t)(bh * 256 + kh * 128 + kd)) * 2048 + t0 + blk * 8,
                &ktA[p][s * 512]);
      } else {
        int i = s - 16, vd = i * 8 + (lane >> 3);
        int blk = (lane & 7) ^ (vd & 7);
        async16(vT + ((size_t)(bh * 512 + vb * 32 + vd)) * 2048 + t0 + blk * 8,
                &vtA[p][i * 512]);
      }
    }
  };

  stage(0, 0);

  for (int n = 0; n < 32; n++) {
    int p = n & 1, t0 = n * 64;
    // write StA <- bf16(S)  (state BEFORE this chunk's update)
#pragma unroll
    for (int a = 0; a < 2; a++)
#pragma unroll
      for (int bb = 0; bb < 2; bb++) {
        int k0 = wave * 32 + a * 16 + quad * 4;
        int vc = bb * 16 + l16;
        f32x4 s = S[a][bb];
        union { bf16 hh[4]; unsigned long long u; } pkk;
        pkk.hh[0] = (bf16)s[0]; pkk.hh[1] = (bf16)s[1];
        pkk.hh[2] = (bf16)s[2]; pkk.hh[3] = (bf16)s[3];
        *(unsigned long long*)&StA[vc * 136 + k0] = pkk.u;
      }
    __syncthreads();  // B1: StA visible; ktA/vtA[p] ready (staged before prev B2 drain)
    if (n < 31) stage(t0 + 64, 1 - p);

    // q fragments direct from global (B-op for A^T, A-op for q@St)
    bf16x8 qf[4];
#pragma unroll
    for (int kk = 0; kk < 4; kk++)
      qf[kk] = *(const bf16x8*)(qrow + (size_t)(t0 + iRow) * 2048 + kk * 32 + quad * 8);

    // A^T[j][i] = sum_kd k_scaled[j][kd] q[i][kd]  (k direct from global)
    f32x4 Dt[4];
#pragma unroll
    for (int jt = 0; jt < 4; jt++) {
      Dt[jt] = (f32x4){0.f, 0.f, 0.f, 0.f};
#pragma unroll
      for (int kk = 0; kk < 4; kk++) {
        bf16x8 kf = *(const bf16x8*)(krow + (size_t)(t0 + jt * 16 + l16) * 2048 + kk * 32 + quad * 8);
        Dt[jt] = MFMA16(kf, qf[kk], Dt[jt]);
      }
    }
    // mask * gamma^(i-63), pack to bf16 pairs
    unsigned pkA[4][2];
#pragma unroll
    for (int jt = 0; jt < 4; jt++) {
      int j0 = jt * 16 + quad * 4;
      union { bf16 hh[2]; unsigned u; } p0, p1;
      p0.hh[0] = (bf16)((iRow >= j0 + 0) ? Dt[jt][0] * ei : 0.f);
      p0.hh[1] = (bf16)((iRow >= j0 + 1) ? Dt[jt][1] * ei : 0.f);
      p1.hh[0] = (bf16)((iRow >= j0 + 2) ? Dt[jt][2] * ei : 0.f);
      p1.hh[1] = (bf16)((iRow >= j0 + 3) ? Dt[jt][3] * ei : 0.f);
      pkA[jt][0] = p0.u; pkA[jt][1] = p1.u;
    }
    // shuffle C-layout A^T -> A-operand of A@v (fixed quad-pair permutation)
    int s0b = ((((quad & 1) << 5) + l16) << 2);
    int s1b = s0b + 64;
    bool hi = (quad >> 1) != 0;
    bf16x8 afA[2];
#pragma unroll
    for (int kk = 0; kk < 2; kk++) {
      unsigned x00 = __builtin_amdgcn_ds_bpermute(s0b, (int)pkA[2 * kk][0]);
      unsigned x01 = __builtin_amdgcn_ds_bpermute(s0b, (int)pkA[2 * kk][1]);
      unsigned x10 = __builtin_amdgcn_ds_bpermute(s0b, (int)pkA[2 * kk + 1][0]);
      unsigned x11 = __builtin_amdgcn_ds_bpermute(s0b, (int)pkA[2 * kk + 1][1]);
      unsigned y00 = __builtin_amdgcn_ds_bpermute(s1b, (int)pkA[2 * kk][0]);
      unsigned y01 = __builtin_amdgcn_ds_bpermute(s1b, (int)pkA[2 * kk][1]);
      unsigned y10 = __builtin_amdgcn_ds_bpermute(s1b, (int)pkA[2 * kk + 1][0]);
      unsigned y11 = __builtin_amdgcn_ds_bpermute(s1b, (int)pkA[2 * kk + 1][1]);
      union { unsigned u[4]; bf16x8 v; } rr;
      rr.u[0] = hi ? x10 : x00;
      rr.u[1] = hi ? x11 : x01;
      rr.u[2] = hi ? y10 : y00;
      rr.u[3] = hi ? y11 : y01;
      afA[kk] = rr.v;
    }

    // o = diag(qd) * (q @ S^T) + A @ v
    f32x4 oacc[2];
#pragma unroll
    for (int nt = 0; nt < 2; nt++) {
      oacc[nt] = (f32x4){0.f, 0.f, 0.f, 0.f};
#pragma unroll
      for (int kk = 0; kk < 4; kk++) {
        bf16x8 stf = *(const bf16x8*)&StA[(nt * 16 + l16) * 136 + kk * 32 + quad * 8];
        oacc[nt] = MFMA16(qf[kk], stf, oacc[nt]);
      }
    }
#pragma unroll
    for (int nt = 0; nt < 2; nt++)
#pragma unroll
      for (int r = 0; r < 4; r++) oacc[nt][r] *= qd[r];

    bf16x8 vtf[2][2];
#pragma unroll
    for (int nt = 0; nt < 2; nt++)
#pragma unroll
      for (int kk = 0; kk < 2; kk++)
        vtf[nt][kk] = *(const bf16x8*)&vtA[p][(nt * 16 + l16) * 64 + ((((kk * 4 + quad) << 3)) ^ sw)];
#pragma unroll
    for (int nt = 0; nt < 2; nt++)
#pragma unroll
      for (int kk = 0; kk < 2; kk++)
        oacc[nt] = MFMA16(afA[kk], vtf[nt][kk], oacc[nt]);

    // store o partial (bf16)
#pragma unroll
    for (int nt = 0; nt < 2; nt++)
#pragma unroll
      for (int r = 0; r < 4; r++) {
        int row = t0 + wave * 16 + quad * 4 + r;
        int col = vb * 32 + nt * 16 + l16;
        oout[((size_t)((b * 2048 + row) * 8 + h)) * 512 + col] = (bf16)oacc[nt][r];
      }

    // S = gC*S + kT_scaled @ v   (fp32 master state in accumulators)
#pragma unroll
    for (int a = 0; a < 2; a++) {
      bf16x8 ktf[2];
#pragma unroll
      for (int kk = 0; kk < 2; kk++)
        ktf[kk] = *(const bf16x8*)&ktA[p][(wave * 32 + a * 16 + l16) * 64 + ((((kk * 4 + quad) << 3)) ^ sw)];
#pragma unroll
      for (int bb = 0; bb < 2; bb++) {
        f32x4 cc = S[a][bb] * gC;
#pragma unroll
        for (int kk = 0; kk < 2; kk++) cc = MFMA16(ktf[kk], vtf[bb][kk], cc);
        S[a][bb] = cc;
      }
    }
    __syncthreads();  // B2: all StA reads done before next iteration's write
  }
}

// ---------------- fused RMSNorm (per 512) + swish gate, bf16 partials in ----------------
__global__ __launch_bounds__(256) void k_normgate(const bf16* __restrict__ o0,
                                                  const bf16* __restrict__ o1,
                                                  const bf16* __restrict__ g,
                                                  const float* __restrict__ gw,
                                                  bf16* __restrict__ og) {
  int tid = threadIdx.x, lane = tid & 63;
  size_t row = (size_t)blockIdx.x * 4 + (tid >> 6);
  size_t base = row * 512;
  float vv[8];
  float ss = 0.f;
#pragma unroll
  for (int hh = 0; hh < 2; hh++) {
    int col = hh * 256 + lane * 4;
    union { bf16 h[4]; uint2 u; } a, b2;
    a.u = *(const uint2*)(o0 + base + col);
    b2.u = *(const uint2*)(o1 + base + col);
#pragma unroll
    for (int jj = 0; jj < 4; jj++) {
      float v = (float)a.h[jj] + (float)b2.h[jj];
      vv[hh * 4 + jj] = v;
      ss += v * v;
    }
  }
#pragma unroll
  for (int off = 1; off < 64; off <<= 1) ss += __shfl_xor(ss, off, 64);
  float rinv = rsqrtf(ss * (1.0f / 512.0f) + 1e-5f);
#pragma unroll
  for (int hh = 0; hh < 2; hh++) {
    int col = hh * 256 + lane * 4;
    union { bf16 h[4]; uint2 u; } gp;
    gp.u = *(const uint2*)(g + base + col);
    union { bf16 h[4]; uint2 u; } op;
#pragma unroll
    for (int jj = 0; jj < 4; jj++) {
      float gg = (float)gp.h[jj];
      float y = vv[hh * 4 + jj] * rinv * gw[col + jj] * (gg / (1.f + expf(-gg)));
      op.h[jj] = (bf16)y;
    }
    *(uint2*)(og + base + col) = op.u;
  }
}

extern "C" void kernel_launch(void* const* d_in, const int* in_sizes, int n_in,
                              void* d_out, int out_size, void* d_ws, size_t ws_size,
                              hipStream_t stream) {
  (void)in_sizes; (void)n_in; (void)out_size; (void)ws_size;
  const float* hs = (const float*)d_in[0];
  const float* Wq = (const float*)d_in[1];
  const float* Wk = (const float*)d_in[2];
  const float* Wv = (const float*)d_in[3];
  const float* Wg = (const float*)d_in[4];
  const float* Wo = (const float*)d_in[5];
  const float* gw = (const float*)d_in[6];
  float* out = (float*)d_out;

  char* ws = (char*)d_ws;
  const size_t MB = 1024 * 1024;
  // overlays (stream-serialized): peak 208 MiB
  bf16* hid = (bf16*)(ws + 0);          // [0,16)    dead after proj GEMM
  bf16* WT  = (bf16*)(ws + 16 * MB);    // [16,64)   12288x2048, dead after proj GEMM
  bf16* qb  = (bf16*)(ws + 64 * MB);    // [64,80)
  bf16* kb  = (bf16*)(ws + 80 * MB);    // [80,96)
  bf16* vbuf= (bf16*)(ws + 96 * MB);    // [96,128)
  bf16* gb  = (bf16*)(ws + 128 * MB);   // [128,160)
  bf16* kT  = (bf16*)(ws + 160 * MB);   // [160,176)  dead after retention
  bf16* vT  = (bf16*)(ws + 176 * MB);   // [176,208)  dead after retention
  bf16* o0  = (bf16*)(ws + 0);          // [0,32)     overlays hid+WT
  bf16* o1  = (bf16*)(ws + 32 * MB);    // [32,64)
  bf16* og  = (bf16*)(ws + 160 * MB);   // [160,192)  overlays kT + vT head
  bf16* WoT = (bf16*)(ws + 192 * MB);   // [192,208)  overlays vT tail

  k_cast<<<8192, 256, 0, stream>>>(hs, hid);
  k_wt_all<<<dim3(128, 64, 4), 256, 0, stream>>>(Wq, Wk, Wv, Wg, WT);

  k_gemm_qkvg<<<dim3(96, 32), 256, 0, stream>>>(hid, WT, qb, kb, vbuf, gb);

  k_rotary2<<<32768, 256, 0, stream>>>(qb, kb);

  k_transpose_bh<<<dim3(8, 64, 16), 256, 0, stream>>>(kb, kT, 256);
  k_transpose_bh<<<dim3(16, 64, 16), 256, 0, stream>>>(vbuf, vT, 512);

  k_retention<<<512, 256, 0, stream>>>(qb, kb, kT, vT, o0, o1);

  k_transpose_cast<<<dim3(64, 128), 256, 0, stream>>>(Wo, WoT, 4096, 2048);
  k_normgate<<<8192, 256, 0, stream>>>(o0, o1, gb, gw, og);
  k_gemm_bt<<<dim3(16, 32), 256, 0, stream>>>(og, WoT, out, 4096, 2048, 4096);
}

// Round 6
// 662.769 us; speedup vs baseline: 1.0823x; 1.0823x over previous
//
#include <hip/hip_runtime.h>
#include <cstdint>
#include <cstddef>

typedef __bf16 bf16;
typedef __bf16 bf16x8 __attribute__((ext_vector_type(8)));
typedef float  f32x4  __attribute__((ext_vector_type(4)));

#define MFMA16(a, b, c) __builtin_amdgcn_mfma_f32_16x16x32_bf16((a), (b), (c), 0, 0, 0)

// async global->LDS, 16B per lane. LDS dest is wave-uniform base + lane*16.
__device__ __forceinline__ void async16(const bf16* g, bf16* l) {
  __builtin_amdgcn_global_load_lds(
      (const __attribute__((address_space(1))) unsigned int*)g,
      (__attribute__((address_space(3))) unsigned int*)l, 16, 0, 0);
}

// ---------------- elementwise cast fp32 -> bf16 (4 elems/thread) ----------------
__global__ __launch_bounds__(256) void k_cast(const float* __restrict__ x, bf16* __restrict__ y) {
  size_t i = ((size_t)blockIdx.x * 256 + threadIdx.x) * 4;
  float4 a = *(const float4*)(x + i);
  union { bf16 h[4]; uint2 u; } pk;
  pk.h[0] = (bf16)a.x; pk.h[1] = (bf16)a.y; pk.h[2] = (bf16)a.z; pk.h[3] = (bf16)a.w;
  *(uint2*)(y + i) = pk.u;
}

// ---------------- batched W[K,N] fp32 -> WT[N,K] bf16 for the 4 input projections ----------------
__global__ __launch_bounds__(256) void k_wt_all(const float* __restrict__ Wq,
                                                const float* __restrict__ Wk,
                                                const float* __restrict__ Wv,
                                                const float* __restrict__ Wg,
                                                bf16* __restrict__ WT) {
  const int K = 2048;
  __shared__ float tile[32][33];
  int z = blockIdx.z;
  const float* W; bf16* dst; int N;
  if (z == 0)      { W = Wq; dst = WT;                          N = 2048; }
  else if (z == 1) { W = Wk; dst = WT + (size_t)2048 * 2048;    N = 2048; }
  else if (z == 2) { W = Wv; dst = WT + (size_t)4096 * 2048;    N = 4096; }
  else             { W = Wg; dst = WT + (size_t)8192 * 2048;    N = 4096; }
  int n0 = blockIdx.x << 5;
  if (n0 >= N) return;
  int k0 = blockIdx.y << 5;
  int r = threadIdx.x >> 5, c = threadIdx.x & 31;
#pragma unroll
  for (int p = 0; p < 4; p++)
    tile[r + p * 8][c] = W[(size_t)(k0 + r + p * 8) * N + n0 + c];
  __syncthreads();
#pragma unroll
  for (int p = 0; p < 4; p++) {
    int nn = r + p * 8;
    dst[(size_t)(n0 + nn) * K + k0 + c] = (bf16)tile[c][nn];
  }
}

// ---------------- W[K,N] fp32 -> WT[N,K] bf16, tiled transpose (single) ----------------
__global__ __launch_bounds__(256) void k_transpose_cast(const float* __restrict__ W,
                                                        bf16* __restrict__ WT, int K, int N) {
  __shared__ float tile[32][33];
  int k0 = blockIdx.y << 5, n0 = blockIdx.x << 5;
  int r = threadIdx.x >> 5, c = threadIdx.x & 31;
#pragma unroll
  for (int p = 0; p < 4; p++)
    tile[r + p * 8][c] = W[(size_t)(k0 + r + p * 8) * N + n0 + c];
  __syncthreads();
#pragma unroll
  for (int p = 0; p < 4; p++) {
    int nn = r + p * 8;
    WT[(size_t)(n0 + nn) * K + k0 + c] = (bf16)tile[c][nn];
  }
}

// ---- per-(b,h) bf16 transpose: src[(b,t),h,d] (d<D) -> dst[(b,h),d,t] ----
__global__ __launch_bounds__(256) void k_transpose_bh(const bf16* __restrict__ src,
                                                      bf16* __restrict__ dst, int D) {
  __shared__ bf16 tile[32][33];
  int bh = blockIdx.z;
  int b = bh >> 3, h = bh & 7;
  int d0 = blockIdx.x << 5, t0 = blockIdx.y << 5;
  int r = threadIdx.x >> 5, c = threadIdx.x & 31;
#pragma unroll
  for (int p = 0; p < 4; p++)
    tile[r + p * 8][c] = src[((size_t)((b * 2048 + t0 + r + p * 8) * 8 + h)) * D + d0 + c];
  __syncthreads();
#pragma unroll
  for (int p = 0; p < 4; p++)
    dst[((size_t)(bh * D + d0 + r + p * 8)) * 2048 + t0 + c] = tile[c][r + p * 8];
}

// ---------------- fused projection GEMM: [4096,2048] x WT[12288,2048]^T ----------------
__global__ __launch_bounds__(256) void k_gemm_qkvg(const bf16* __restrict__ A,
                                                   const bf16* __restrict__ Bt,
                                                   bf16* __restrict__ qb, bf16* __restrict__ kb,
                                                   bf16* __restrict__ vbuf, bf16* __restrict__ gb) {
  const int K = 2048;
  __shared__ bf16 a_lds[128 * 64];
  __shared__ bf16 b_lds[128 * 64];
  int tid = threadIdx.x;
  int wave = tid >> 6, lane = tid & 63, quad = lane >> 4, l16 = lane & 15;
  int wr = wave >> 1, wc = wave & 1;
  int m0 = blockIdx.y << 7, n0 = blockIdx.x << 7;
  f32x4 acc[4][4] = {};
  int rl = tid >> 3;                       // local row 0..31 (row&7 == rl&7 for all i)
  int sb = (tid & 7) ^ (rl & 7);           // swizzled source block
  const bf16* ag = A + (size_t)(m0 + rl) * K + sb * 8;
  const bf16* bg = Bt + (size_t)(n0 + rl) * K + sb * 8;
  bf16* al = a_lds + wave * 512;
  bf16* bl = b_lds + wave * 512;
  int sw = (l16 & 7) << 3;                 // read-side XOR (bf16 elems)
  for (int kt = 0; kt < K; kt += 64) {
#pragma unroll
    for (int i = 0; i < 4; i++) {
      async16(ag + (size_t)i * 32 * K, al + i * 2048);
      async16(bg + (size_t)i * 32 * K, bl + i * 2048);
    }
    ag += 64; bg += 64;
    __syncthreads();
#pragma unroll
    for (int kk = 0; kk < 2; kk++) {
      int bo = ((kk * 4 + quad) << 3) ^ sw;
      bf16x8 af[4], bfv[4];
#pragma unroll
      for (int mt = 0; mt < 4; mt++)
        af[mt] = *(const bf16x8*)&a_lds[(wr * 64 + mt * 16 + l16) * 64 + bo];
#pragma unroll
      for (int nt = 0; nt < 4; nt++)
        bfv[nt] = *(const bf16x8*)&b_lds[(wc * 64 + nt * 16 + l16) * 64 + bo];
#pragma unroll
      for (int mt = 0; mt < 4; mt++)
#pragma unroll
        for (int nt = 0; nt < 4; nt++)
          acc[mt][nt] = MFMA16(af[mt], bfv[nt], acc[mt][nt]);
    }
    __syncthreads();
  }
  // segmented epilogue (wave-uniform segment select)
  bf16* dst; int ldd, c0;
  if (n0 < 2048)       { dst = qb;   ldd = 2048; c0 = n0; }
  else if (n0 < 4096)  { dst = kb;   ldd = 2048; c0 = n0 - 2048; }
  else if (n0 < 8192)  { dst = vbuf; ldd = 4096; c0 = n0 - 4096; }
  else                 { dst = gb;   ldd = 4096; c0 = n0 - 8192; }
#pragma unroll
  for (int mt = 0; mt < 4; mt++)
#pragma unroll
    for (int nt = 0; nt < 4; nt++)
#pragma unroll
      for (int r = 0; r < 4; r++) {
        int row = m0 + wr * 64 + mt * 16 + quad * 4 + r;
        int col = c0 + wc * 64 + nt * 16 + l16;
        dst[(size_t)row * ldd + col] = (bf16)acc[mt][nt][r];
      }
}

// ---------------- GEMM: C[M,N] = A[M,K] * Bt[N,K]^T  (bf16 in, fp32 out) ----------------
__global__ __launch_bounds__(256) void k_gemm_bt(const bf16* __restrict__ A,
                                                 const bf16* __restrict__ Bt,
                                                 float* __restrict__ C, int M, int N, int K) {
  __shared__ bf16 a_lds[128 * 64];
  __shared__ bf16 b_lds[128 * 64];
  int tid = threadIdx.x;
  int wave = tid >> 6, lane = tid & 63, quad = lane >> 4, l16 = lane & 15;
  int wr = wave >> 1, wc = wave & 1;
  int m0 = blockIdx.y << 7, n0 = blockIdx.x << 7;
  f32x4 acc[4][4] = {};
  int rl = tid >> 3;
  int sb = (tid & 7) ^ (rl & 7);
  const bf16* ag = A + (size_t)(m0 + rl) * K + sb * 8;
  const bf16* bg = Bt + (size_t)(n0 + rl) * K + sb * 8;
  bf16* al = a_lds + wave * 512;
  bf16* bl = b_lds + wave * 512;
  int sw = (l16 & 7) << 3;
  for (int kt = 0; kt < K; kt += 64) {
#pragma unroll
    for (int i = 0; i < 4; i++) {
      async16(ag + (size_t)i * 32 * K, al + i * 2048);
      async16(bg + (size_t)i * 32 * K, bl + i * 2048);
    }
    ag += 64; bg += 64;
    __syncthreads();
#pragma unroll
    for (int kk = 0; kk < 2; kk++) {
      int bo = ((kk * 4 + quad) << 3) ^ sw;
      bf16x8 af[4], bfv[4];
#pragma unroll
      for (int mt = 0; mt < 4; mt++)
        af[mt] = *(const bf16x8*)&a_lds[(wr * 64 + mt * 16 + l16) * 64 + bo];
#pragma unroll
      for (int nt = 0; nt < 4; nt++)
        bfv[nt] = *(const bf16x8*)&b_lds[(wc * 64 + nt * 16 + l16) * 64 + bo];
#pragma unroll
      for (int mt = 0; mt < 4; mt++)
#pragma unroll
        for (int nt = 0; nt < 4; nt++)
          acc[mt][nt] = MFMA16(af[mt], bfv[nt], acc[mt][nt]);
    }
    __syncthreads();
  }
#pragma unroll
  for (int mt = 0; mt < 4; mt++)
#pragma unroll
    for (int nt = 0; nt < 4; nt++)
#pragma unroll
      for (int r = 0; r < 4; r++) {
        int row = m0 + wr * 64 + mt * 16 + quad * 4 + r;
        int col = n0 + wc * 64 + nt * 16 + l16;
        C[(size_t)row * N + col] = acc[mt][nt][r];
      }
}

// ------- merged rotary (in-place, bf16): blocks [0,16384) -> q (*DK^-0.5),
// [16384,32768) -> k (fold gamma^(63-(t&63))) -------
__global__ __launch_bounds__(256) void k_rotary2(bf16* __restrict__ q, bf16* __restrict__ k) {
  int bid = blockIdx.x;
  bf16* x; int kmode;
  if (bid < 16384) { x = q; kmode = 0; }
  else             { x = k; kmode = 1; bid -= 16384; }
  int tid = threadIdx.x;
  int row = bid * 2 + (tid >> 7);
  int j = tid & 127;
  int t = (row >> 3) & 2047;
  int h = row & 7;
  float scale;
  if (kmode) {
    float lg = log2f(1.f - exp2f(-5.f - (float)h));
    scale = exp2f(lg * (float)(63 - (t & 63)));
  } else {
    scale = 0.0625f;
  }
  float inv = exp2f(-0.10381025296522976f * (float)j);
  float ang = (float)t * inv;
  float s, c;
  sincosf(ang, &s, &c);
  size_t base = (size_t)row * 256;
  float x1 = (float)x[base + j], x2 = (float)x[base + j + 128];
  x[base + j]       = (bf16)((x1 * c - x2 * s) * scale);
  x[base + j + 128] = (bf16)((x2 * c + x1 * s) * scale);
}

// ---------------- retention scan: full LDS staging, single-buffered, 2 WG/CU ----------------
// grid 512: gid = vb*32 + (b*16 + h*2 + kh); vb in [0,16) owns 32 v-cols; kh owns 128 kd
// rows (partials sum in normgate). q/k/kT/vT staged via async16 with XOR block swizzle
// into SINGLE buffers (qA 16K + kA 16K + ktA 16K + vtA 4K + StA 8.5K = 60.5 KB -> 2 WG/CU).
// Two barriers per chunk: B1 (staging + StA visible), B2 (all reads done) then stage(n+1).
// The co-resident second WG covers the B2->B1 staging latency.
__global__ __launch_bounds__(256) void k_retention(const bf16* __restrict__ q,
                                                   const bf16* __restrict__ k,
                                                   const bf16* __restrict__ kT,
                                                   const bf16* __restrict__ vT,
                                                   bf16* __restrict__ o0,
                                                   bf16* __restrict__ o1) {
  __shared__ bf16 qA[64 * 128];   // [c][kd]
  __shared__ bf16 kA[64 * 128];   // [c][kd] (scaled k)
  __shared__ bf16 ktA[128 * 64];  // [kd][c]
  __shared__ bf16 vtA[32 * 64];   // [vd][c]
  __shared__ bf16 StA[32 * 136];  // [vd][kd] +8 pad (VGPR-written)

  int gid = blockIdx.x;
  int kh = gid & 1, h = (gid >> 1) & 7, b = (gid >> 4) & 1, vb = gid >> 5;
  int bh = b * 8 + h;
  bf16* oout = kh ? o1 : o0;
  int tid = threadIdx.x, lane = tid & 63, wave = tid >> 6, quad = lane >> 4, l16 = lane & 15;
  float gamma = 1.f - exp2f(-5.f - (float)h);
  float lg = log2f(gamma);
  float gC = exp2f(64.f * lg);
  int iRow = wave * 16 + l16;                       // i for A^T(n) and A@v(m)
  float ei = exp2f(lg * (float)(iRow - 63));
  float qd[4];
#pragma unroll
  for (int r = 0; r < 4; r++) qd[r] = exp2f(lg * (float)(wave * 16 + quad * 4 + r + 1));
  int sw = (l16 & 7) << 3;                          // read-side XOR (bf16 elems)

  f32x4 S[2][2];  // a(kd-tile: wave*32+a*16) x bb(vd-tile: bb*16)
#pragma unroll
  for (int a = 0; a < 2; a++)
#pragma unroll
    for (int bb = 0; bb < 2; bb++) S[a][bb] = (f32x4){0.f, 0.f, 0.f, 0.f};

  // async staging of one chunk (52 x 1KB instrs over 4 waves)
  auto stage = [&](int t0) {
#pragma unroll 1
    for (int s = wave; s < 52; s += 4) {
      if (s < 16) {
        int c = s * 4 + (lane >> 4);
        int blk = (lane & 15) ^ (c & 7);
        async16(q + (((size_t)((b * 2048 + t0 + c) * 8 + h)) << 8) + kh * 128 + blk * 8,
                &qA[s * 512]);
      } else if (s < 32) {
        int i = s - 16, c = i * 4 + (lane >> 4);
        int blk = (lane & 15) ^ (c & 7);
        async16(k + (((size_t)((b * 2048 + t0 + c) * 8 + h)) << 8) + kh * 128 + blk * 8,
                &kA[i * 512]);
      } else if (s < 48) {
        int i = s - 32, kd = i * 8 + (lane >> 3);
        int blk = (lane & 7) ^ (kd & 7);
        async16(kT + ((size_t)(bh * 256 + kh * 128 + kd)) * 2048 + t0 + blk * 8,
                &ktA[i * 512]);
      } else {
        int i = s - 48, vd = i * 8 + (lane >> 3);
        int blk = (lane & 7) ^ (vd & 7);
        async16(vT + ((size_t)(bh * 512 + vb * 32 + vd)) * 2048 + t0 + blk * 8,
                &vtA[i * 512]);
      }
    }
  };

  stage(0);

  for (int n = 0; n < 32; n++) {
    int t0 = n * 64;
    // StA <- bf16(S)  (state BEFORE this chunk's update)
#pragma unroll
    for (int a = 0; a < 2; a++)
#pragma unroll
      for (int bb = 0; bb < 2; bb++) {
        int k0 = wave * 32 + a * 16 + quad * 4;
        int vc = bb * 16 + l16;
        f32x4 s = S[a][bb];
        union { bf16 hh[4]; unsigned long long u; } pkk;
        pkk.hh[0] = (bf16)s[0]; pkk.hh[1] = (bf16)s[1];
        pkk.hh[2] = (bf16)s[2]; pkk.hh[3] = (bf16)s[3];
        *(unsigned long long*)&StA[vc * 136 + k0] = pkk.u;
      }
    __syncthreads();  // B1: staging vmcnt drained + StA visible

    // q fragments (B-op for A^T, A-op for q@St)
    bf16x8 qf[4];
#pragma unroll
    for (int kk = 0; kk < 4; kk++)
      qf[kk] = *(const bf16x8*)&qA[iRow * 128 + ((((kk * 4 + quad) << 3)) ^ sw)];

    // A^T[j][i] = sum_kd k_scaled[j][kd] q[i][kd]
    f32x4 Dt[4];
#pragma unroll
    for (int jt = 0; jt < 4; jt++) {
      Dt[jt] = (f32x4){0.f, 0.f, 0.f, 0.f};
#pragma unroll
      for (int kk = 0; kk < 4; kk++) {
        bf16x8 kf = *(const bf16x8*)&kA[(jt * 16 + l16) * 128 + ((((kk * 4 + quad) << 3)) ^ sw)];
        Dt[jt] = MFMA16(kf, qf[kk], Dt[jt]);
      }
    }
    // mask * gamma^(i-63), pack to bf16 pairs
    unsigned pkA[4][2];
#pragma unroll
    for (int jt = 0; jt < 4; jt++) {
      int j0 = jt * 16 + quad * 4;
      union { bf16 hh[2]; unsigned u; } p0, p1;
      p0.hh[0] = (bf16)((iRow >= j0 + 0) ? Dt[jt][0] * ei : 0.f);
      p0.hh[1] = (bf16)((iRow >= j0 + 1) ? Dt[jt][1] * ei : 0.f);
      p1.hh[0] = (bf16)((iRow >= j0 + 2) ? Dt[jt][2] * ei : 0.f);
      p1.hh[1] = (bf16)((iRow >= j0 + 3) ? Dt[jt][3] * ei : 0.f);
      pkA[jt][0] = p0.u; pkA[jt][1] = p1.u;
    }
    // shuffle C-layout A^T -> A-operand of A@v (fixed quad-pair permutation)
    int s0b = ((((quad & 1) << 5) + l16) << 2);
    int s1b = s0b + 64;
    bool hi = (quad >> 1) != 0;
    bf16x8 afA[2];
#pragma unroll
    for (int kk = 0; kk < 2; kk++) {
      unsigned x00 = __builtin_amdgcn_ds_bpermute(s0b, (int)pkA[2 * kk][0]);
      unsigned x01 = __builtin_amdgcn_ds_bpermute(s0b, (int)pkA[2 * kk][1]);
      unsigned x10 = __builtin_amdgcn_ds_bpermute(s0b, (int)pkA[2 * kk + 1][0]);
      unsigned x11 = __builtin_amdgcn_ds_bpermute(s0b, (int)pkA[2 * kk + 1][1]);
      unsigned y00 = __builtin_amdgcn_ds_bpermute(s1b, (int)pkA[2 * kk][0]);
      unsigned y01 = __builtin_amdgcn_ds_bpermute(s1b, (int)pkA[2 * kk][1]);
      unsigned y10 = __builtin_amdgcn_ds_bpermute(s1b, (int)pkA[2 * kk + 1][0]);
      unsigned y11 = __builtin_amdgcn_ds_bpermute(s1b, (int)pkA[2 * kk + 1][1]);
      union { unsigned u[4]; bf16x8 v; } rr;
      rr.u[0] = hi ? x10 : x00;
      rr.u[1] = hi ? x11 : x01;
      rr.u[2] = hi ? y10 : y00;
      rr.u[3] = hi ? y11 : y01;
      afA[kk] = rr.v;
    }

    // o = diag(qd) * (q @ S^T) + A @ v
    f32x4 oacc[2];
#pragma unroll
    for (int nt = 0; nt < 2; nt++) {
      oacc[nt] = (f32x4){0.f, 0.f, 0.f, 0.f};
#pragma unroll
      for (int kk = 0; kk < 4; kk++) {
        bf16x8 stf = *(const bf16x8*)&StA[(nt * 16 + l16) * 136 + kk * 32 + quad * 8];
        oacc[nt] = MFMA16(qf[kk], stf, oacc[nt]);
      }
    }
#pragma unroll
    for (int nt = 0; nt < 2; nt++)
#pragma unroll
      for (int r = 0; r < 4; r++) oacc[nt][r] *= qd[r];

    bf16x8 vtf[2][2];
#pragma unroll
    for (int nt = 0; nt < 2; nt++)
#pragma unroll
      for (int kk = 0; kk < 2; kk++)
        vtf[nt][kk] = *(const bf16x8*)&vtA[(nt * 16 + l16) * 64 + ((((kk * 4 + quad) << 3)) ^ sw)];
#pragma unroll
    for (int nt = 0; nt < 2; nt++)
#pragma unroll
      for (int kk = 0; kk < 2; kk++)
        oacc[nt] = MFMA16(afA[kk], vtf[nt][kk], oacc[nt]);

    // store o partial (bf16)
#pragma unroll
    for (int nt = 0; nt < 2; nt++)
#pragma unroll
      for (int r = 0; r < 4; r++) {
        int row = t0 + wave * 16 + quad * 4 + r;
        int col = vb * 32 + nt * 16 + l16;
        oout[((size_t)((b * 2048 + row) * 8 + h)) * 512 + col] = (bf16)oacc[nt][r];
      }

    // S = gC*S + kT_scaled @ v   (fp32 master state in accumulators)
#pragma unroll
    for (int a = 0; a < 2; a++) {
      bf16x8 ktf[2];
#pragma unroll
      for (int kk = 0; kk < 2; kk++)
        ktf[kk] = *(const bf16x8*)&ktA[(wave * 32 + a * 16 + l16) * 64 + ((((kk * 4 + quad) << 3)) ^ sw)];
#pragma unroll
      for (int bb = 0; bb < 2; bb++) {
        f32x4 cc = S[a][bb] * gC;
#pragma unroll
        for (int kk = 0; kk < 2; kk++) cc = MFMA16(ktf[kk], vtf[bb][kk], cc);
        S[a][bb] = cc;
      }
    }
    __syncthreads();  // B2: all LDS reads of this chunk done
    if (n < 31) stage(t0 + 64);
  }
}

// ---------------- fused RMSNorm (per 512) + swish gate, bf16 partials in ----------------
__global__ __launch_bounds__(256) void k_normgate(const bf16* __restrict__ o0,
                                                  const bf16* __restrict__ o1,
                                                  const bf16* __restrict__ g,
                                                  const float* __restrict__ gw,
                                                  bf16* __restrict__ og) {
  int tid = threadIdx.x, lane = tid & 63;
  size_t row = (size_t)blockIdx.x * 4 + (tid >> 6);
  size_t base = row * 512;
  float vv[8];
  float ss = 0.f;
#pragma unroll
  for (int hh = 0; hh < 2; hh++) {
    int col = hh * 256 + lane * 4;
    union { bf16 h[4]; uint2 u; } a, b2;
    a.u = *(const uint2*)(o0 + base + col);
    b2.u = *(const uint2*)(o1 + base + col);
#pragma unroll
    for (int jj = 0; jj < 4; jj++) {
      float v = (float)a.h[jj] + (float)b2.h[jj];
      vv[hh * 4 + jj] = v;
      ss += v * v;
    }
  }
#pragma unroll
  for (int off = 1; off < 64; off <<= 1) ss += __shfl_xor(ss, off, 64);
  float rinv = rsqrtf(ss * (1.0f / 512.0f) + 1e-5f);
#pragma unroll
  for (int hh = 0; hh < 2; hh++) {
    int col = hh * 256 + lane * 4;
    union { bf16 h[4]; uint2 u; } gp;
    gp.u = *(const uint2*)(g + base + col);
    union { bf16 h[4]; uint2 u; } op;
#pragma unroll
    for (int jj = 0; jj < 4; jj++) {
      float gg = (float)gp.h[jj];
      float y = vv[hh * 4 + jj] * rinv * gw[col + jj] * (gg / (1.f + expf(-gg)));
      op.h[jj] = (bf16)y;
    }
    *(uint2*)(og + base + col) = op.u;
  }
}

extern "C" void kernel_launch(void* const* d_in, const int* in_sizes, int n_in,
                              void* d_out, int out_size, void* d_ws, size_t ws_size,
                              hipStream_t stream) {
  (void)in_sizes; (void)n_in; (void)out_size; (void)ws_size;
  const float* hs = (const float*)d_in[0];
  const float* Wq = (const float*)d_in[1];
  const float* Wk = (const float*)d_in[2];
  const float* Wv = (const float*)d_in[3];
  const float* Wg = (const float*)d_in[4];
  const float* Wo = (const float*)d_in[5];
  const float* gw = (const float*)d_in[6];
  float* out = (float*)d_out;

  char* ws = (char*)d_ws;
  const size_t MB = 1024 * 1024;
  // overlays (stream-serialized): peak 208 MiB
  bf16* hid = (bf16*)(ws + 0);          // [0,16)    dead after proj GEMM
  bf16* WT  = (bf16*)(ws + 16 * MB);    // [16,64)   12288x2048, dead after proj GEMM
  bf16* qb  = (bf16*)(ws + 64 * MB);    // [64,80)
  bf16* kb  = (bf16*)(ws + 80 * MB);    // [80,96)
  bf16* vbuf= (bf16*)(ws + 96 * MB);    // [96,128)
  bf16* gb  = (bf16*)(ws + 128 * MB);   // [128,160)
  bf16* kT  = (bf16*)(ws + 160 * MB);   // [160,176)  dead after retention
  bf16* vT  = (bf16*)(ws + 176 * MB);   // [176,208)  dead after retention
  bf16* o0  = (bf16*)(ws + 0);          // [0,32)     overlays hid+WT
  bf16* o1  = (bf16*)(ws + 32 * MB);    // [32,64)
  bf16* og  = (bf16*)(ws + 160 * MB);   // [160,192)  overlays kT + vT head
  bf16* WoT = (bf16*)(ws + 192 * MB);   // [192,208)  overlays vT tail

  k_cast<<<8192, 256, 0, stream>>>(hs, hid);
  k_wt_all<<<dim3(128, 64, 4), 256, 0, stream>>>(Wq, Wk, Wv, Wg, WT);

  k_gemm_qkvg<<<dim3(96, 32), 256, 0, stream>>>(hid, WT, qb, kb, vbuf, gb);

  k_rotary2<<<32768, 256, 0, stream>>>(qb, kb);

  k_transpose_bh<<<dim3(8, 64, 16), 256, 0, stream>>>(kb, kT, 256);
  k_transpose_bh<<<dim3(16, 64, 16), 256, 0, stream>>>(vbuf, vT, 512);

  k_retention<<<512, 256, 0, stream>>>(qb, kb, kT, vT, o0, o1);

  k_transpose_cast<<<dim3(64, 128), 256, 0, stream>>>(Wo, WoT, 4096, 2048);
  k_normgate<<<8192, 256, 0, stream>>>(o0, o1, gb, gw, og);
  k_gemm_bt<<<dim3(16, 32), 256, 0, stream>>>(og, WoT, out, 4096, 2048, 4096);
}